// Round 4
// baseline (132.244 us; speedup 1.0000x reference)
//
#include <hip/hip_runtime.h>
#include <hip/hip_bf16.h>

// QKVAttention: qkv (4,1536,2048) fp32, N_HEADS=8, ch=64, 32 total heads.
// S[t,s] = (1/8) sum_c q[c,t] k[c,s]; P = softmax over t (COLUMN softmax);
// a[c,t] = sum_s P[t,s] v[c,s].
//
//  K1 convert : Qt[h][t][c], Kt[h][s][c] bf16, transposed, XOR-pre-swizzled,
//               scale sqrt(0.125*log2e) baked in (so exp(S) == exp2(S')).
//  K2 stats   : barrier-free; per (head,128-s): l[s] = sum_t exp2(S') with
//               Q fragments loaded straight to registers; then Vb = V/l bf16.
//  K3 attn    : barrier-free, NO LDS. K/V fragments loaded global->VGPR
//               (all waves read identical fragments -> L1 broadcast),
//               ping-pong register double-buffer (unroll-2).
//               S'^T via mfma(K,Q) 32x32x16, P=exp2 in-register,
//               cvt_pk+permlane32_swap -> PV B-frags, A += Vb * P^T.

#define SEQ   2048
#define CHD   64
#define NHB   32
#define SCALE_QK 0.42466090f   // sqrt(0.125 * log2(e))

typedef short bf16x8 __attribute__((ext_vector_type(8)));
typedef float f32x4  __attribute__((ext_vector_type(4)));
typedef float f32x16 __attribute__((ext_vector_type(16)));
typedef unsigned int   u32x4 __attribute__((ext_vector_type(4)));
typedef unsigned short us8   __attribute__((ext_vector_type(8)));

__device__ __forceinline__ unsigned short f2bf(float f) {
    unsigned int u = __builtin_bit_cast(unsigned int, f);
    u += 0x7FFFu + ((u >> 16) & 1u);   // RNE
    return (unsigned short)(u >> 16);
}

__device__ __forceinline__ unsigned cvtpk(float a, float b) {
    unsigned r;
    asm("v_cvt_pk_bf16_f32 %0, %1, %2" : "=v"(r) : "v"(a), "v"(b));
    return r;
}
__device__ __forceinline__ void plswap(unsigned &a, unsigned &b) {
    asm("v_permlane32_swap_b32 %0, %1" : "+v"(a), "+v"(b));
}

#define ZERO16 {0.f,0.f,0.f,0.f,0.f,0.f,0.f,0.f,0.f,0.f,0.f,0.f,0.f,0.f,0.f,0.f}

// ------------------------------------------------ K1: transpose+convert Q,K
__global__ __launch_bounds__(256) void convert_qk(
    const float* __restrict__ qkv, unsigned short* __restrict__ Qt,
    unsigned short* __restrict__ Kt)
{
    __shared__ float Tl[64][129];
    const int bid = blockIdx.x;
    const int head = bid >> 4, t0 = (bid & 15) * 128;
    const int b = head >> 3, h = head & 7;
    const float* base = qkv + (size_t)(b * 1536 + h * 192) * SEQ;
    const int tid = threadIdx.x;
#pragma unroll
    for (int pp = 0; pp < 2; ++pp) {
        const float* src = base + (size_t)(pp ? CHD : 0) * SEQ;
        unsigned short* dst = (pp ? Kt : Qt) + (size_t)head * SEQ * CHD;
        if (pp) __syncthreads();
        for (int e = tid; e < 8192; e += 256) {
            int c = e >> 7, ti = e & 127;
            Tl[c][ti] = src[(size_t)c * SEQ + t0 + ti];
        }
        __syncthreads();
        for (int g = tid; g < 1024; g += 256) {
            int t = g >> 3, cg = g & 7;
            us8 u;
#pragma unroll
            for (int j = 0; j < 8; ++j) u[j] = f2bf(Tl[cg * 8 + j][t] * SCALE_QK);
            *(us8*)(dst + (size_t)(t0 + t) * 64 + ((cg * 8) ^ ((t & 7) << 3))) = u;
        }
    }
}

// ------------------------------------------------ K2: column sums + V scale
__global__ __launch_bounds__(256) void stats3_kernel(
    const float* __restrict__ qkv, const unsigned short* __restrict__ Qt,
    const unsigned short* __restrict__ Kt, unsigned short* __restrict__ Vb)
{
    __shared__ float rlb[128];
    const int bid = blockIdx.x;
    const int bs  = ((bid & 7) << 6) | (bid >> 3);   // XCD swizzle (512%8==0)
    const int head = bs >> 4, s0 = (bs & 15) * 128;
    const int b = head >> 3, h = head & 7;
    const unsigned short* Qh = Qt + (size_t)head * SEQ * CHD;
    const unsigned short* Kh = Kt + (size_t)head * SEQ * CHD;
    const int tid = threadIdx.x, w = tid >> 6, l = tid & 63, lo5 = l & 31, hi = l >> 5;
    const int rsw = (lo5 & 7) << 3;
    const int smine = s0 + w * 32 + lo5;

    bf16x8 kfr[4];
#pragma unroll
    for (int kc = 0; kc < 4; ++kc)
        kfr[kc] = *(const bf16x8*)(Kh + (size_t)smine * 64 + (((kc << 4) + (hi << 3)) ^ rsw));

    float lacc[4] = {0.f, 0.f, 0.f, 0.f};

    auto do_tile = [&](const bf16x8* qa) {
        f32x16 sacc = ZERO16;
#pragma unroll
        for (int kc = 0; kc < 4; ++kc)
            sacc = __builtin_amdgcn_mfma_f32_32x32x16_bf16(qa[kc], kfr[kc], sacc, 0, 0, 0);
#pragma unroll
        for (int r = 0; r < 16; ++r) lacc[r & 3] += __builtin_exp2f(sacc[r]);
    };

    bf16x8 qn[4], qa[4];
#pragma unroll
    for (int kc = 0; kc < 4; ++kc)
        qn[kc] = *(const bf16x8*)(Qh + (size_t)lo5 * 64 + (((kc << 4) + (hi << 3)) ^ rsw));

    for (int tc = 0; tc < 63; ++tc) {
#pragma unroll
        for (int kc = 0; kc < 4; ++kc) qa[kc] = qn[kc];
#pragma unroll
        for (int kc = 0; kc < 4; ++kc)
            qn[kc] = *(const bf16x8*)(Qh + (size_t)((tc + 1) * 32 + lo5) * 64 +
                                      (((kc << 4) + (hi << 3)) ^ rsw));
        do_tile(qa);
    }
    do_tile(qn);

    float l_run = (lacc[0] + lacc[1]) + (lacc[2] + lacc[3]);
    l_run += __shfl_xor(l_run, 32);
    if (l < 32) rlb[w * 32 + lo5] = 1.0f / l_run;
    __syncthreads();

    // V: scale by 1/l[s], bf16, pre-swizzle within each 64-s block (vectorized)
    const float* vp = qkv + (size_t)(b * 1536 + h * 192 + 2 * CHD) * SEQ;
    unsigned short* Vh = Vb + (size_t)head * SEQ * CHD;   // layout [c][2048]
    for (int g = tid; g < 1024; g += 256) {
        int c = g >> 4, si8 = (g & 15) * 8;
        const float* vrow = vp + (size_t)c * SEQ + s0 + si8;
        f32x4 v0 = *(const f32x4*)(vrow);
        f32x4 v1 = *(const f32x4*)(vrow + 4);
        us8 u;
#pragma unroll
        for (int j = 0; j < 4; ++j) u[j]     = f2bf(v0[j] * rlb[si8 + j]);
#pragma unroll
        for (int j = 0; j < 4; ++j) u[4 + j] = f2bf(v1[j] * rlb[si8 + 4 + j]);
        int swb = (si8 & ~63) | ((si8 & 63) ^ ((c & 7) << 3));
        *(us8*)(Vh + (size_t)c * SEQ + s0 + swb) = u;
    }
}

// ------------------------------------------------ K3: attention (no LDS)
__global__ __launch_bounds__(256) void attn4_kernel(
    const unsigned short* __restrict__ Qt, const unsigned short* __restrict__ Kt,
    const unsigned short* __restrict__ Vb, float* __restrict__ out)
{
    const int bid = blockIdx.x;
    const int bs  = ((bid & 7) << 6) | (bid >> 3);   // XCD swizzle
    const int head = bs >> 4, t0 = (bs & 15) * 128;
    const int b = head >> 3, h = head & 7;
    const int tid = threadIdx.x, w = tid >> 6, l = tid & 63, lo5 = l & 31, hi = l >> 5;
    const int rsw = (lo5 & 7) << 3;
    const unsigned short* Qh = Qt + (size_t)head * SEQ * CHD;
    const unsigned short* Kh = Kt + (size_t)head * SEQ * CHD;
    const unsigned short* Vh = Vb + (size_t)head * SEQ * CHD;
    const int tmine = t0 + w * 32 + lo5;

    // Q B-fragments, hoisted for the whole kernel (cols t = tmine)
    bf16x8 qf[4];
#pragma unroll
    for (int kc = 0; kc < 4; ++kc)
        qf[kc] = *(const bf16x8*)(Qh + (size_t)tmine * 64 + (((kc << 4) + (hi << 3)) ^ rsw));

    f32x16 acc[2] = {ZERO16, ZERO16};

    // fragment loaders: identical across the block's 4 waves -> L1 broadcast
    auto load_k = [&](int sc, bf16x8* kf) {
#pragma unroll
        for (int st = 0; st < 2; ++st)
#pragma unroll
            for (int kc = 0; kc < 4; ++kc)
                kf[st * 4 + kc] = *(const bf16x8*)(
                    Kh + (size_t)(sc * 64 + st * 32 + lo5) * 64 +
                    (((kc << 4) + (hi << 3)) ^ rsw));
    };
    auto load_v = [&](int sc, bf16x8* vf) {
#pragma unroll
        for (int ct = 0; ct < 2; ++ct)
#pragma unroll
            for (int q = 0; q < 4; ++q)
                vf[ct * 4 + q] = *(const bf16x8*)(
                    Vh + (size_t)(ct * 32 + lo5) * SEQ + sc * 64 +
                    (((q << 4) + (hi << 3)) ^ rsw));
    };
    auto compute = [&](const bf16x8* kf, const bf16x8* vf) {
#pragma unroll
        for (int st = 0; st < 2; ++st) {
            f32x16 sacc = ZERO16;
#pragma unroll
            for (int kc = 0; kc < 4; ++kc)
                sacc = __builtin_amdgcn_mfma_f32_32x32x16_bf16(kf[st * 4 + kc], qf[kc], sacc, 0, 0, 0);
            float p[16];
#pragma unroll
            for (int r = 0; r < 16; ++r) p[r] = __builtin_exp2f(sacc[r]);
            unsigned w0 = cvtpk(p[0], p[1]),   w1 = cvtpk(p[2], p[3]);
            unsigned w2 = cvtpk(p[4], p[5]),   w3 = cvtpk(p[6], p[7]);
            unsigned w4 = cvtpk(p[8], p[9]),   w5 = cvtpk(p[10], p[11]);
            unsigned w6 = cvtpk(p[12], p[13]), w7 = cvtpk(p[14], p[15]);
            plswap(w0, w2); plswap(w1, w3); plswap(w4, w6); plswap(w5, w7);
            bf16x8 pfA = __builtin_bit_cast(bf16x8, (u32x4){w0, w1, w2, w3});
            bf16x8 pfB = __builtin_bit_cast(bf16x8, (u32x4){w4, w5, w6, w7});
#pragma unroll
            for (int ct = 0; ct < 2; ++ct) {
                acc[ct] = __builtin_amdgcn_mfma_f32_32x32x16_bf16(vf[ct * 4 + st * 2 + 0], pfA, acc[ct], 0, 0, 0);
                acc[ct] = __builtin_amdgcn_mfma_f32_32x32x16_bf16(vf[ct * 4 + st * 2 + 1], pfB, acc[ct], 0, 0, 0);
            }
        }
    };

    // ping-pong register double-buffer, unroll-2 (no cross-copy moves)
    bf16x8 kA[8], vA[8], kB[8], vB[8];
    load_k(0, kA); load_v(0, vA);
    for (int sc = 0; sc < 32; sc += 2) {
        if (sc + 1 < 32) { load_k(sc + 1, kB); load_v(sc + 1, vB); }
        compute(kA, vA);
        if (sc + 2 < 32) { load_k(sc + 2, kA); load_v(sc + 2, vA); }
        compute(kB, vB);
    }

    float* op = out + (size_t)(b * 512 + h * 64) * SEQ;
#pragma unroll
    for (int ct = 0; ct < 2; ++ct)
#pragma unroll
        for (int r = 0; r < 16; ++r) {
            int c = ct * 32 + (r & 3) + ((r >> 2) << 3) + (hi << 2);
            op[(size_t)c * SEQ + tmine] = acc[ct][r];
        }
}

// ================================================================ fallback
// (round-1 proven path, used only if ws is too small for the bf16 buffers)

__device__ __forceinline__ bf16x8 lds_frag(const unsigned short* base, int row, int el) {
    int e = el ^ ((row & 7) << 3);
    return *(const bf16x8*)(base + row * 64 + e);
}

__global__ __launch_bounds__(256) void qkv_stats_kernel(
    const float* __restrict__ qkv, float* __restrict__ m_ws, float* __restrict__ rl_ws)
{
    __shared__ __attribute__((aligned(16))) unsigned short Kl[128 * 64];
    __shared__ __attribute__((aligned(16))) unsigned short Ql[64 * 64];
    const int head = blockIdx.x >> 4, stile = blockIdx.x & 15, s0 = stile * 128;
    const int b = head >> 3, h = head & 7;
    const float* qp = qkv + (size_t)(b * 1536 + h * 192) * SEQ;
    const float* kp = qp + (size_t)CHD * SEQ;
    const int tid = threadIdx.x, w = tid >> 6, l = tid & 63, lg = l >> 4, lr = l & 15;
    for (int idx = tid; idx < 128 * 64; idx += 256) {
        int s = idx & 127, c = idx >> 7;
        Kl[s * 64 + (c ^ ((s & 7) << 3))] = f2bf(kp[(size_t)c * SEQ + s0 + s]);
    }
    float m_run[2] = {-__builtin_inff(), -__builtin_inff()};
    float l_run[2] = {0.f, 0.f};
    for (int chunk = 0; chunk < 32; ++chunk) {
        const int t0 = chunk * 64;
        __syncthreads();
        for (int idx = tid; idx < 64 * 64; idx += 256) {
            int t = idx & 63, c = idx >> 6;
            Ql[t * 64 + (c ^ ((t & 7) << 3))] = f2bf(qp[(size_t)c * SEQ + t0 + t]);
        }
        __syncthreads();
#pragma unroll
        for (int ntl = 0; ntl < 2; ++ntl) {
            const int srow = 16 * (2 * w + ntl) + lr;
            float vals[16];
#pragma unroll
            for (int mt = 0; mt < 4; ++mt) {
                f32x4 sacc = {0.f, 0.f, 0.f, 0.f};
#pragma unroll
                for (int kk = 0; kk < 2; ++kk) {
                    bf16x8 a  = lds_frag(Ql, 16 * mt + lr, 32 * kk + 8 * lg);
                    bf16x8 bk = lds_frag(Kl, srow,         32 * kk + 8 * lg);
                    sacc = __builtin_amdgcn_mfma_f32_16x16x32_bf16(a, bk, sacc, 0, 0, 0);
                }
#pragma unroll
                for (int j = 0; j < 4; ++j) vals[mt * 4 + j] = sacc[j] * 0.125f;
            }
            float cm = vals[0];
#pragma unroll
            for (int i = 1; i < 16; ++i) cm = fmaxf(cm, vals[i]);
            cm = fmaxf(cm, __shfl_xor(cm, 16));
            cm = fmaxf(cm, __shfl_xor(cm, 32));
            float newm = fmaxf(m_run[ntl], cm);
            l_run[ntl] *= __expf(m_run[ntl] - newm);
            m_run[ntl] = newm;
            float ps = 0.f;
#pragma unroll
            for (int i = 0; i < 16; ++i) ps += __expf(vals[i] - newm);
            ps += __shfl_xor(ps, 16);
            ps += __shfl_xor(ps, 32);
            l_run[ntl] += ps;
        }
    }
    if (lg == 0) {
#pragma unroll
        for (int ntl = 0; ntl < 2; ++ntl) {
            int sg = s0 + 16 * (2 * w + ntl) + lr;
            m_ws[head * SEQ + sg]  = m_run[ntl];
            rl_ws[head * SEQ + sg] = 1.0f / l_run[ntl];
        }
    }
}

__global__ __launch_bounds__(256) void qkv_attn_kernel(
    const float* __restrict__ qkv, const float* __restrict__ m_ws,
    const float* __restrict__ rl_ws, float* __restrict__ out)
{
    __shared__ __attribute__((aligned(16))) unsigned short Ql[128 * 64];
    __shared__ __attribute__((aligned(16))) unsigned short Kl[64 * 64];
    __shared__ __attribute__((aligned(16))) unsigned short Vl[64 * 64];
    __shared__ __attribute__((aligned(16))) unsigned short Pl[128 * 64];
    const int head = blockIdx.x >> 4, ttile = blockIdx.x & 15, t0 = ttile * 128;
    const int b = head >> 3, h = head & 7;
    const float* qp  = qkv + (size_t)(b * 1536 + h * 192) * SEQ;
    const float* kp  = qp + (size_t)CHD * SEQ;
    const float* vp  = qp + (size_t)(2 * CHD) * SEQ;
    const float* mh  = m_ws  + head * SEQ;
    const float* rlh = rl_ws + head * SEQ;
    const int tid = threadIdx.x, w = tid >> 6, l = tid & 63, lg = l >> 4, lr = l & 15;
    for (int idx = tid; idx < 128 * 64; idx += 256) {
        int t = idx & 127, c = idx >> 7;
        Ql[t * 64 + (c ^ ((t & 7) << 3))] = f2bf(qp[(size_t)c * SEQ + t0 + t]);
    }
    f32x4 acc[4][2];
#pragma unroll
    for (int i = 0; i < 4; ++i)
#pragma unroll
        for (int j = 0; j < 2; ++j) acc[i][j] = (f32x4){0.f, 0.f, 0.f, 0.f};
    for (int sc = 0; sc < 32; ++sc) {
        const int s0 = sc * 64;
        __syncthreads();
        for (int idx = tid; idx < 64 * 64; idx += 256) {
            int s = idx & 63, c = idx >> 6;
            Kl[s * 64 + (c ^ ((s & 7) << 3))] = f2bf(kp[(size_t)c * SEQ + s0 + s]);
            Vl[c * 64 + (s ^ ((c & 7) << 3))] = f2bf(vp[(size_t)c * SEQ + s0 + s] * rlh[s0 + s]);
        }
        __syncthreads();
        float msv[4];
#pragma unroll
        for (int nts = 0; nts < 4; ++nts) msv[nts] = mh[s0 + 16 * nts + lr];
#pragma unroll
        for (int mts = 0; mts < 2; ++mts) {
            const int trowbase = 16 * (2 * w + mts);
#pragma unroll
            for (int nts = 0; nts < 4; ++nts) {
                f32x4 sa = {0.f, 0.f, 0.f, 0.f};
#pragma unroll
                for (int kk = 0; kk < 2; ++kk) {
                    bf16x8 a  = lds_frag(Ql, trowbase + lr, 32 * kk + 8 * lg);
                    bf16x8 bk = lds_frag(Kl, 16 * nts + lr, 32 * kk + 8 * lg);
                    sa = __builtin_amdgcn_mfma_f32_16x16x32_bf16(a, bk, sa, 0, 0, 0);
                }
                const int scol = 16 * nts + lr;
#pragma unroll
                for (int j = 0; j < 4; ++j) {
                    int trow = trowbase + 4 * lg + j;
                    float p = __expf(sa[j] * 0.125f - msv[nts]);
                    Pl[trow * 64 + (scol ^ ((trow & 7) << 3))] = f2bf(p);
                }
            }
        }
#pragma unroll
        for (int mt = 0; mt < 4; ++mt) {
#pragma unroll
            for (int ntl = 0; ntl < 2; ++ntl) {
                const int trow = 16 * (2 * w + ntl);
#pragma unroll
                for (int kk = 0; kk < 2; ++kk) {
                    bf16x8 a  = lds_frag(Vl, 16 * mt + lr, 32 * kk + 8 * lg);
                    bf16x8 bp = lds_frag(Pl, trow + lr,    32 * kk + 8 * lg);
                    acc[mt][ntl] = __builtin_amdgcn_mfma_f32_16x16x32_bf16(a, bp, acc[mt][ntl], 0, 0, 0);
                }
            }
        }
    }
    float* op = out + (size_t)(b * 512 + h * 64) * SEQ;
#pragma unroll
    for (int mt = 0; mt < 4; ++mt) {
#pragma unroll
        for (int ntl = 0; ntl < 2; ++ntl) {
            int tcol = t0 + 16 * (2 * w + ntl) + lr;
#pragma unroll
            for (int j = 0; j < 4; ++j) {
                int c = 16 * mt + 4 * lg + j;
                op[(size_t)c * SEQ + tcol] = acc[mt][ntl][j];
            }
        }
    }
}

// ================================================================ launch
extern "C" void kernel_launch(void* const* d_in, const int* in_sizes, int n_in,
                              void* d_out, int out_size, void* d_ws, size_t ws_size,
                              hipStream_t stream) {
    const float* qkv = (const float*)d_in[0];
    float* out = (float*)d_out;
    (void)in_sizes; (void)n_in; (void)out_size;

    const size_t need = (size_t)3 * NHB * SEQ * CHD * 2;   // 24 MB bf16 buffers
    if (ws_size >= need) {
        unsigned short* Qt = (unsigned short*)d_ws;
        unsigned short* Kt = Qt + (size_t)NHB * SEQ * CHD;
        unsigned short* Vb = Kt + (size_t)NHB * SEQ * CHD;
        convert_qk   <<<dim3(NHB * 16), dim3(256), 0, stream>>>(qkv, Qt, Kt);
        stats3_kernel<<<dim3(NHB * 16), dim3(256), 0, stream>>>(qkv, Qt, Kt, Vb);
        attn4_kernel <<<dim3(NHB * 16), dim3(256), 0, stream>>>(Qt, Kt, Vb, out);
    } else {
        float* m_ws  = (float*)d_ws;
        float* rl_ws = m_ws + (size_t)NHB * SEQ;
        qkv_stats_kernel<<<dim3(NHB * 16), dim3(256), 0, stream>>>(qkv, m_ws, rl_ws);
        qkv_attn_kernel <<<dim3(NHB * 16), dim3(256), 0, stream>>>(qkv, m_ws, rl_ws, out);
    }
}

// Round 5
// 105.700 us; speedup vs baseline: 1.2511x; 1.2511x over previous
//
#include <hip/hip_runtime.h>
#include <hip/hip_bf16.h>

// QKVAttention: qkv (4,1536,2048) fp32, N_HEADS=8, ch=64, 32 total heads.
// S[t,s] = (1/8) sum_c q[c,t] k[c,s]; P = softmax over t (COLUMN softmax);
// a[c,t] = sum_s P[t,s] v[c,s].
//
//  K1 convert : Qt[h][t][c], Kt[h][s][c] bf16, transposed, XOR-pre-swizzled,
//               scale sqrt(0.125*log2e) baked in (so exp(S) == exp2(S')).
//  K2 stats4  : block = 64 s x all t; wave w owns t-quarter (no shared-operand
//               redundancy). l[s] = sum_t exp2(S'); small LDS reduce; then
//               Vb = V/l bf16 (pre-swizzled per 32-s block).
//  K3 attn5   : block = 64 t x all s; wave w owns s-chunks 4j+w (32 s each).
//               K/V read ONCE per block; wave-private LDS dbuf staged via
//               global_load_lds + per-wave counted vmcnt -> ZERO barriers in
//               the main loop. S'^T = mfma(K,Q) 32x32x16, P = exp2 in-reg,
//               cvt_pk+permlane32_swap -> PV B-frags, partial A += Vb*P^T;
//               one-barrier cross-wave reduction in (reused) LDS at the end.

#define SEQ   2048
#define CHD   64
#define NHB   32
#define SCALE_QK 0.42466090f   // sqrt(0.125 * log2(e))

typedef short bf16x8 __attribute__((ext_vector_type(8)));
typedef float f32x4  __attribute__((ext_vector_type(4)));
typedef float f32x16 __attribute__((ext_vector_type(16)));
typedef unsigned int   u32x4 __attribute__((ext_vector_type(4)));
typedef unsigned short us8   __attribute__((ext_vector_type(8)));

__device__ __forceinline__ unsigned short f2bf(float f) {
    unsigned int u = __builtin_bit_cast(unsigned int, f);
    u += 0x7FFFu + ((u >> 16) & 1u);   // RNE
    return (unsigned short)(u >> 16);
}

__device__ __forceinline__ void gl_lds16(const void* g, void* l) {
    __builtin_amdgcn_global_load_lds(
        (const __attribute__((address_space(1))) void*)g,
        (__attribute__((address_space(3))) void*)l, 16, 0, 0);
}

__device__ __forceinline__ unsigned cvtpk(float a, float b) {
    unsigned r;
    asm("v_cvt_pk_bf16_f32 %0, %1, %2" : "=v"(r) : "v"(a), "v"(b));
    return r;
}
__device__ __forceinline__ void plswap(unsigned &a, unsigned &b) {
    asm("v_permlane32_swap_b32 %0, %1" : "+v"(a), "+v"(b));
}

#define ZERO16 {0.f,0.f,0.f,0.f,0.f,0.f,0.f,0.f,0.f,0.f,0.f,0.f,0.f,0.f,0.f,0.f}

// ------------------------------------------------ K1: transpose+convert Q,K
__global__ __launch_bounds__(256) void convert_qk(
    const float* __restrict__ qkv, unsigned short* __restrict__ Qt,
    unsigned short* __restrict__ Kt)
{
    __shared__ float Tl[64][129];
    const int bid = blockIdx.x;
    const int head = bid >> 4, t0 = (bid & 15) * 128;
    const int b = head >> 3, h = head & 7;
    const float* base = qkv + (size_t)(b * 1536 + h * 192) * SEQ;
    const int tid = threadIdx.x;
#pragma unroll
    for (int pp = 0; pp < 2; ++pp) {
        const float* src = base + (size_t)(pp ? CHD : 0) * SEQ;
        unsigned short* dst = (pp ? Kt : Qt) + (size_t)head * SEQ * CHD;
        if (pp) __syncthreads();
        for (int e = tid; e < 8192; e += 256) {
            int c = e >> 7, ti = e & 127;
            Tl[c][ti] = src[(size_t)c * SEQ + t0 + ti];
        }
        __syncthreads();
        for (int g = tid; g < 1024; g += 256) {
            int t = g >> 3, cg = g & 7;
            us8 u;
#pragma unroll
            for (int j = 0; j < 8; ++j) u[j] = f2bf(Tl[cg * 8 + j][t] * SCALE_QK);
            *(us8*)(dst + (size_t)(t0 + t) * 64 + ((cg * 8) ^ ((t & 7) << 3))) = u;
        }
    }
}

// ------------------------------------------------ K2: column sums + V scale
// block: 64 s x 2048 t; wave w handles t in [w*512, (w+1)*512)
__global__ __launch_bounds__(256, 4) void stats4_kernel(
    const float* __restrict__ qkv, const unsigned short* __restrict__ Qt,
    const unsigned short* __restrict__ Kt, unsigned short* __restrict__ Vb)
{
    __shared__ float lds_l[4][2][32];
    __shared__ float rlb[64];
    const int bid = blockIdx.x;
    const int bs  = ((bid & 7) << 7) | (bid >> 3);   // XCD swizzle (1024%8==0)
    const int head = bs >> 5, s0 = (bs & 31) * 64;
    const int b = head >> 3, h = head & 7;
    const unsigned short* Qh = Qt + (size_t)head * SEQ * CHD;
    const unsigned short* Kh = Kt + (size_t)head * SEQ * CHD;
    const int tid = threadIdx.x, w = tid >> 6, l = tid & 63, lo5 = l & 31, hi = l >> 5;
    const int rsw = (lo5 & 7) << 3;

    // K fragments for this block's 64 s, register-resident
    bf16x8 kfr[8];
#pragma unroll
    for (int ss = 0; ss < 2; ++ss)
#pragma unroll
        for (int kc = 0; kc < 4; ++kc)
            kfr[ss * 4 + kc] = *(const bf16x8*)(
                Kh + (size_t)(s0 + ss * 32 + lo5) * 64 + (((kc << 4) + (hi << 3)) ^ rsw));

    const unsigned short* qbase = Qh + (size_t)(w * 512) * 64;   // t-quarter
    float lp[2][4] = {{0.f,0.f,0.f,0.f},{0.f,0.f,0.f,0.f}};

    auto do_tile = [&](const bf16x8* qa) {
#pragma unroll
        for (int ss = 0; ss < 2; ++ss) {
            f32x16 sacc = ZERO16;
#pragma unroll
            for (int kc = 0; kc < 4; ++kc)
                sacc = __builtin_amdgcn_mfma_f32_32x32x16_bf16(qa[kc], kfr[ss * 4 + kc], sacc, 0, 0, 0);
#pragma unroll
            for (int r = 0; r < 16; ++r) lp[ss][r & 3] += __builtin_exp2f(sacc[r]);
        }
    };

    bf16x8 qn[4], qa[4];
#pragma unroll
    for (int kc = 0; kc < 4; ++kc)
        qn[kc] = *(const bf16x8*)(qbase + (size_t)lo5 * 64 + (((kc << 4) + (hi << 3)) ^ rsw));
    for (int tc = 0; tc < 15; ++tc) {
#pragma unroll
        for (int kc = 0; kc < 4; ++kc) qa[kc] = qn[kc];
#pragma unroll
        for (int kc = 0; kc < 4; ++kc)
            qn[kc] = *(const bf16x8*)(qbase + (size_t)((tc + 1) * 32 + lo5) * 64 +
                                      (((kc << 4) + (hi << 3)) ^ rsw));
        do_tile(qa);
    }
    do_tile(qn);

    float l0 = (lp[0][0] + lp[0][1]) + (lp[0][2] + lp[0][3]);
    float l1 = (lp[1][0] + lp[1][1]) + (lp[1][2] + lp[1][3]);
    l0 += __shfl_xor(l0, 32);
    l1 += __shfl_xor(l1, 32);
    if (l < 32) { lds_l[w][0][lo5] = l0; lds_l[w][1][lo5] = l1; }
    __syncthreads();
    if (tid < 64) {
        int ss = tid >> 5, si = tid & 31;
        float s = (lds_l[0][ss][si] + lds_l[1][ss][si]) +
                  (lds_l[2][ss][si] + lds_l[3][ss][si]);
        rlb[tid] = 1.0f / s;
    }
    __syncthreads();

    // V: scale by 1/l[s], bf16, pre-swizzle within each 32-s block
    const float* vp = qkv + (size_t)(b * 1536 + h * 192 + 2 * CHD) * SEQ;
    unsigned short* Vh = Vb + (size_t)head * SEQ * CHD;   // layout [c][2048]
    for (int g = tid; g < 512; g += 256) {
        int c = g >> 3, si8 = (g & 7) * 8;
        const float* vrow = vp + (size_t)c * SEQ + s0 + si8;
        f32x4 v0 = *(const f32x4*)(vrow);
        f32x4 v1 = *(const f32x4*)(vrow + 4);
        us8 u;
#pragma unroll
        for (int j = 0; j < 4; ++j) u[j]     = f2bf(v0[j] * rlb[si8 + j]);
#pragma unroll
        for (int j = 0; j < 4; ++j) u[4 + j] = f2bf(v1[j] * rlb[si8 + 4 + j]);
        int swb = (si8 & ~31) | ((si8 & 31) ^ (((c >> 1) & 3) << 3));
        *(us8*)(Vh + (size_t)c * SEQ + s0 + swb) = u;
    }
}

// ------------------------------------------------ K3: attention (s-split)
// block: 64 t x 2048 s; wave w owns 32-s chunks cj = 4j+w, j=0..15.
__global__ __launch_bounds__(256, 2) void attn5_kernel(
    const unsigned short* __restrict__ Qt, const unsigned short* __restrict__ Kt,
    const unsigned short* __restrict__ Vb, float* __restrict__ out)
{
    __shared__ __attribute__((aligned(16))) unsigned short KV[4][8192]; // 16KB/wave
    const int bid = blockIdx.x;
    const int bs  = ((bid & 7) << 7) | (bid >> 3);   // XCD swizzle (1024%8==0)
    const int head = bs >> 5, t0 = (bs & 31) * 64;
    const int b = head >> 3, h = head & 7;
    const int tid = threadIdx.x, w = tid >> 6, l = tid & 63, lo5 = l & 31, hi = l >> 5;
    const int rsw = (lo5 & 7) << 3;
    const unsigned short* Qh = Qt + (size_t)head * SEQ * CHD;
    const char* Khb = (const char*)(Kt + (size_t)head * SEQ * CHD);
    const char* Vhb = (const char*)(Vb + (size_t)head * SEQ * CHD);

    // Q B-fragments for the block's 64 t, register-resident
    bf16x8 qf[8];
#pragma unroll
    for (int ts = 0; ts < 2; ++ts)
#pragma unroll
        for (int kc = 0; kc < 4; ++kc)
            qf[ts * 4 + kc] = *(const bf16x8*)(
                Qh + (size_t)(t0 + ts * 32 + lo5) * 64 + (((kc << 4) + (hi << 3)) ^ rsw));

    f32x16 acc[2][2] = {{ZERO16, ZERO16}, {ZERO16, ZERO16}};   // [ct][tset]

    unsigned short* mybuf = &KV[w][0];   // wave-private 16 KB (2 x 8 KB bufs)

    // stage chunk cj (32 s): K 4 KB + V 4 KB, 8 x global_load_lds(16B)
    auto stage = [&](int p, int cj) {
        unsigned short* kb = mybuf + p * 4096;
        unsigned short* vb = mybuf + p * 4096 + 2048;
#pragma unroll
        for (int i = 0; i < 4; ++i)
            gl_lds16(Khb + (size_t)cj * 4096 + i * 1024 + l * 16, kb + i * 512);
#pragma unroll
        for (int i = 0; i < 4; ++i) {
            int c = i * 16 + (l >> 2);
            gl_lds16(Vhb + (size_t)c * 4096 + cj * 64 + (l & 3) * 16, vb + i * 512);
        }
    };

    auto compute = [&](int p) {
        const unsigned short* kb = mybuf + p * 4096;
        const unsigned short* vb = mybuf + p * 4096 + 2048;
        bf16x8 kf[4], vf[4];
#pragma unroll
        for (int kc = 0; kc < 4; ++kc)
            kf[kc] = *(const bf16x8*)(kb + lo5 * 64 + (((kc << 4) + (hi << 3)) ^ rsw));
#pragma unroll
        for (int ct = 0; ct < 2; ++ct)
#pragma unroll
            for (int ks = 0; ks < 2; ++ks)
                vf[ct * 2 + ks] = *(const bf16x8*)(
                    vb + (ct * 32 + lo5) * 32 +
                    (((ks << 4) + (hi << 3)) ^ (((lo5 >> 1) & 3) << 3)));
#pragma unroll
        for (int ts = 0; ts < 2; ++ts) {
            f32x16 sacc = ZERO16;
#pragma unroll
            for (int kc = 0; kc < 4; ++kc)
                sacc = __builtin_amdgcn_mfma_f32_32x32x16_bf16(kf[kc], qf[ts * 4 + kc], sacc, 0, 0, 0);
            float p16[16];
#pragma unroll
            for (int r = 0; r < 16; ++r) p16[r] = __builtin_exp2f(sacc[r]);
            unsigned w0 = cvtpk(p16[0],  p16[1]),  w1 = cvtpk(p16[2],  p16[3]);
            unsigned w2 = cvtpk(p16[4],  p16[5]),  w3 = cvtpk(p16[6],  p16[7]);
            unsigned w4 = cvtpk(p16[8],  p16[9]),  w5 = cvtpk(p16[10], p16[11]);
            unsigned w6 = cvtpk(p16[12], p16[13]), w7 = cvtpk(p16[14], p16[15]);
            plswap(w0, w2); plswap(w1, w3); plswap(w4, w6); plswap(w5, w7);
            bf16x8 pfA = __builtin_bit_cast(bf16x8, (u32x4){w0, w1, w2, w3});
            bf16x8 pfB = __builtin_bit_cast(bf16x8, (u32x4){w4, w5, w6, w7});
#pragma unroll
            for (int ct = 0; ct < 2; ++ct) {
                acc[ct][ts] = __builtin_amdgcn_mfma_f32_32x32x16_bf16(vf[ct * 2 + 0], pfA, acc[ct][ts], 0, 0, 0);
                acc[ct][ts] = __builtin_amdgcn_mfma_f32_32x32x16_bf16(vf[ct * 2 + 1], pfB, acc[ct][ts], 0, 0, 0);
            }
        }
    };

    stage(0, w);
    stage(1, 4 + w);
    for (int j = 0; j < 15; ++j) {
        asm volatile("s_waitcnt vmcnt(8)" ::: "memory");
        compute(j & 1);
        if (j < 14) {
            __builtin_amdgcn_sched_barrier(0);
            stage(j & 1, (j + 2) * 4 + w);
        }
    }
    asm volatile("s_waitcnt vmcnt(0)" ::: "memory");
    compute(1);

    // ---- cross-wave reduction: [sw][ct*2+ts][rg][lane] f32x4 slots (64 KB)
    float* lred = (float*)&KV[0][0];
#pragma unroll
    for (int ct = 0; ct < 2; ++ct)
#pragma unroll
        for (int ts = 0; ts < 2; ++ts)
#pragma unroll
            for (int rg = 0; rg < 4; ++rg) {
                f32x4 v = {acc[ct][ts][rg * 4 + 0], acc[ct][ts][rg * 4 + 1],
                           acc[ct][ts][rg * 4 + 2], acc[ct][ts][rg * 4 + 3]};
                *(f32x4*)&lred[((((w * 4 + ct * 2 + ts) * 4) + rg) * 64 + l) * 4] = v;
            }
    __syncthreads();
    const int myct = w >> 1, myts = w & 1;
    float* op = out + (size_t)(b * 512 + h * 64) * SEQ;
#pragma unroll
    for (int rg = 0; rg < 4; ++rg) {
        f32x4 r0 = *(f32x4*)&lred[((((0 * 4 + myct * 2 + myts) * 4) + rg) * 64 + l) * 4];
        f32x4 r1 = *(f32x4*)&lred[((((1 * 4 + myct * 2 + myts) * 4) + rg) * 64 + l) * 4];
        f32x4 r2 = *(f32x4*)&lred[((((2 * 4 + myct * 2 + myts) * 4) + rg) * 64 + l) * 4];
        f32x4 r3 = *(f32x4*)&lred[((((3 * 4 + myct * 2 + myts) * 4) + rg) * 64 + l) * 4];
        f32x4 rs = (r0 + r1) + (r2 + r3);
        int t = t0 + myts * 32 + lo5;
#pragma unroll
        for (int q = 0; q < 4; ++q) {
            int c = myct * 32 + q + 8 * rg + 4 * hi;
            op[(size_t)c * SEQ + t] = rs[q];
        }
    }
}

// ================================================================ fallback
// (round-1 proven path, used only if ws is too small for the bf16 buffers)

__device__ __forceinline__ bf16x8 lds_frag(const unsigned short* base, int row, int el) {
    int e = el ^ ((row & 7) << 3);
    return *(const bf16x8*)(base + row * 64 + e);
}

__global__ __launch_bounds__(256) void qkv_stats_kernel(
    const float* __restrict__ qkv, float* __restrict__ m_ws, float* __restrict__ rl_ws)
{
    __shared__ __attribute__((aligned(16))) unsigned short Kl[128 * 64];
    __shared__ __attribute__((aligned(16))) unsigned short Ql[64 * 64];
    const int head = blockIdx.x >> 4, stile = blockIdx.x & 15, s0 = stile * 128;
    const int b = head >> 3, h = head & 7;
    const float* qp = qkv + (size_t)(b * 1536 + h * 192) * SEQ;
    const float* kp = qp + (size_t)CHD * SEQ;
    const int tid = threadIdx.x, w = tid >> 6, l = tid & 63, lg = l >> 4, lr = l & 15;
    for (int idx = tid; idx < 128 * 64; idx += 256) {
        int s = idx & 127, c = idx >> 7;
        Kl[s * 64 + (c ^ ((s & 7) << 3))] = f2bf(kp[(size_t)c * SEQ + s0 + s]);
    }
    float m_run[2] = {-__builtin_inff(), -__builtin_inff()};
    float l_run[2] = {0.f, 0.f};
    for (int chunk = 0; chunk < 32; ++chunk) {
        const int t0 = chunk * 64;
        __syncthreads();
        for (int idx = tid; idx < 64 * 64; idx += 256) {
            int t = idx & 63, c = idx >> 6;
            Ql[t * 64 + (c ^ ((t & 7) << 3))] = f2bf(qp[(size_t)c * SEQ + t0 + t]);
        }
        __syncthreads();
#pragma unroll
        for (int ntl = 0; ntl < 2; ++ntl) {
            const int srow = 16 * (2 * w + ntl) + lr;
            float vals[16];
#pragma unroll
            for (int mt = 0; mt < 4; ++mt) {
                f32x4 sacc = {0.f, 0.f, 0.f, 0.f};
#pragma unroll
                for (int kk = 0; kk < 2; ++kk) {
                    bf16x8 a  = lds_frag(Ql, 16 * mt + lr, 32 * kk + 8 * lg);
                    bf16x8 bk = lds_frag(Kl, srow,         32 * kk + 8 * lg);
                    sacc = __builtin_amdgcn_mfma_f32_16x16x32_bf16(a, bk, sacc, 0, 0, 0);
                }
#pragma unroll
                for (int j = 0; j < 4; ++j) vals[mt * 4 + j] = sacc[j] * 0.125f;
            }
            float cm = vals[0];
#pragma unroll
            for (int i = 1; i < 16; ++i) cm = fmaxf(cm, vals[i]);
            cm = fmaxf(cm, __shfl_xor(cm, 16));
            cm = fmaxf(cm, __shfl_xor(cm, 32));
            float newm = fmaxf(m_run[ntl], cm);
            l_run[ntl] *= __expf(m_run[ntl] - newm);
            m_run[ntl] = newm;
            float ps = 0.f;
#pragma unroll
            for (int i = 0; i < 16; ++i) ps += __expf(vals[i] - newm);
            ps += __shfl_xor(ps, 16);
            ps += __shfl_xor(ps, 32);
            l_run[ntl] += ps;
        }
    }
    if (lg == 0) {
#pragma unroll
        for (int ntl = 0; ntl < 2; ++ntl) {
            int sg = s0 + 16 * (2 * w + ntl) + lr;
            m_ws[head * SEQ + sg]  = m_run[ntl];
            rl_ws[head * SEQ + sg] = 1.0f / l_run[ntl];
        }
    }
}

__global__ __launch_bounds__(256) void qkv_attn_kernel(
    const float* __restrict__ qkv, const float* __restrict__ m_ws,
    const float* __restrict__ rl_ws, float* __restrict__ out)
{
    __shared__ __attribute__((aligned(16))) unsigned short Ql[128 * 64];
    __shared__ __attribute__((aligned(16))) unsigned short Kl[64 * 64];
    __shared__ __attribute__((aligned(16))) unsigned short Vl[64 * 64];
    __shared__ __attribute__((aligned(16))) unsigned short Pl[128 * 64];
    const int head = blockIdx.x >> 4, ttile = blockIdx.x & 15, t0 = ttile * 128;
    const int b = head >> 3, h = head & 7;
    const float* qp  = qkv + (size_t)(b * 1536 + h * 192) * SEQ;
    const float* kp  = qp + (size_t)CHD * SEQ;
    const float* vp  = qp + (size_t)(2 * CHD) * SEQ;
    const float* mh  = m_ws  + head * SEQ;
    const float* rlh = rl_ws + head * SEQ;
    const int tid = threadIdx.x, w = tid >> 6, l = tid & 63, lg = l >> 4, lr = l & 15;
    for (int idx = tid; idx < 128 * 64; idx += 256) {
        int t = idx & 127, c = idx >> 7;
        Ql[t * 64 + (c ^ ((t & 7) << 3))] = f2bf(qp[(size_t)c * SEQ + t0 + t]);
    }
    f32x4 acc[4][2];
#pragma unroll
    for (int i = 0; i < 4; ++i)
#pragma unroll
        for (int j = 0; j < 2; ++j) acc[i][j] = (f32x4){0.f, 0.f, 0.f, 0.f};
    for (int sc = 0; sc < 32; ++sc) {
        const int s0 = sc * 64;
        __syncthreads();
        for (int idx = tid; idx < 64 * 64; idx += 256) {
            int s = idx & 63, c = idx >> 6;
            Kl[s * 64 + (c ^ ((s & 7) << 3))] = f2bf(kp[(size_t)c * SEQ + s0 + s]);
            Vl[c * 64 + (s ^ ((c & 7) << 3))] = f2bf(vp[(size_t)c * SEQ + s0 + s] * rlh[s0 + s]);
        }
        __syncthreads();
        float msv[4];
#pragma unroll
        for (int nts = 0; nts < 4; ++nts) msv[nts] = mh[s0 + 16 * nts + lr];
#pragma unroll
        for (int mts = 0; mts < 2; ++mts) {
            const int trowbase = 16 * (2 * w + mts);
#pragma unroll
            for (int nts = 0; nts < 4; ++nts) {
                f32x4 sa = {0.f, 0.f, 0.f, 0.f};
#pragma unroll
                for (int kk = 0; kk < 2; ++kk) {
                    bf16x8 a  = lds_frag(Ql, trowbase + lr, 32 * kk + 8 * lg);
                    bf16x8 bk = lds_frag(Kl, 16 * nts + lr, 32 * kk + 8 * lg);
                    sa = __builtin_amdgcn_mfma_f32_16x16x32_bf16(a, bk, sa, 0, 0, 0);
                }
                const int scol = 16 * nts + lr;
#pragma unroll
                for (int j = 0; j < 4; ++j) {
                    int trow = trowbase + 4 * lg + j;
                    float p = __expf(sa[j] * 0.125f - msv[nts]);
                    Pl[trow * 64 + (scol ^ ((trow & 7) << 3))] = f2bf(p);
                }
            }
        }
#pragma unroll
        for (int mt = 0; mt < 4; ++mt) {
#pragma unroll
            for (int ntl = 0; ntl < 2; ++ntl) {
                const int trow = 16 * (2 * w + ntl);
#pragma unroll
                for (int kk = 0; kk < 2; ++kk) {
                    bf16x8 a  = lds_frag(Vl, 16 * mt + lr, 32 * kk + 8 * lg);
                    bf16x8 bp = lds_frag(Pl, trow + lr,    32 * kk + 8 * lg);
                    acc[mt][ntl] = __builtin_amdgcn_mfma_f32_16x16x32_bf16(a, bp, acc[mt][ntl], 0, 0, 0);
                }
            }
        }
    }
    float* op = out + (size_t)(b * 512 + h * 64) * SEQ;
#pragma unroll
    for (int mt = 0; mt < 4; ++mt) {
#pragma unroll
        for (int ntl = 0; ntl < 2; ++ntl) {
            int tcol = t0 + 16 * (2 * w + ntl) + lr;
#pragma unroll
            for (int j = 0; j < 4; ++j) {
                int c = 16 * mt + 4 * lg + j;
                op[(size_t)c * SEQ + tcol] = acc[mt][ntl][j];
            }
        }
    }
}

// ================================================================ launch
extern "C" void kernel_launch(void* const* d_in, const int* in_sizes, int n_in,
                              void* d_out, int out_size, void* d_ws, size_t ws_size,
                              hipStream_t stream) {
    const float* qkv = (const float*)d_in[0];
    float* out = (float*)d_out;
    (void)in_sizes; (void)n_in; (void)out_size;

    const size_t need = (size_t)3 * NHB * SEQ * CHD * 2;   // 24 MB bf16 buffers
    if (ws_size >= need) {
        unsigned short* Qt = (unsigned short*)d_ws;
        unsigned short* Kt = Qt + (size_t)NHB * SEQ * CHD;
        unsigned short* Vb = Kt + (size_t)NHB * SEQ * CHD;
        convert_qk   <<<dim3(NHB * 16), dim3(256), 0, stream>>>(qkv, Qt, Kt);
        stats4_kernel<<<dim3(1024),     dim3(256), 0, stream>>>(qkv, Qt, Kt, Vb);
        attn5_kernel <<<dim3(1024),     dim3(256), 0, stream>>>(Qt, Kt, Vb, out);
    } else {
        float* m_ws  = (float*)d_ws;
        float* rl_ws = m_ws + (size_t)NHB * SEQ;
        qkv_stats_kernel<<<dim3(NHB * 16), dim3(256), 0, stream>>>(qkv, m_ws, rl_ws);
        qkv_attn_kernel <<<dim3(NHB * 16), dim3(256), 0, stream>>>(qkv, m_ws, rl_ws, out);
    }
}